// Round 8
// baseline (412.423 us; speedup 1.0000x reference)
//
#include <hip/hip_runtime.h>

typedef _Float16 f16;
typedef _Float16 f16x8 __attribute__((ext_vector_type(8)));
typedef _Float16 f16x4 __attribute__((ext_vector_type(4)));
typedef float f32x4 __attribute__((ext_vector_type(4)));
typedef float f32x16 __attribute__((ext_vector_type(16)));

#define MFMA16(A, B, C) __builtin_amdgcn_mfma_f32_16x16x32_f16((A), (B), (C), 0, 0, 0)
#define MFMA32(A, B, C) __builtin_amdgcn_mfma_f32_32x32x16_f16((A), (B), (C), 0, 0, 0)
// legacy K=16 shape: A/B are f16x4; A-layout == our S^T accumulator C-layout.
#define MFMA16K16(A, B, C) __builtin_amdgcn_mfma_f32_16x16x16f16((A), (B), (C), 0, 0, 0)

// async global->LDS, 16B per lane, dest = wave-uniform base + lane*16
__device__ __forceinline__ void async16(void* lds, const void* gp) {
    __builtin_amdgcn_global_load_lds(
        (__attribute__((address_space(1))) void*)(gp),
        (__attribute__((address_space(3))) void*)(lds), 16, 0, 0);
}

// ---------------- fp32 -> fp16 cast (vectorized) ----------------
__global__ __launch_bounds__(256) void k_convert(const float* __restrict__ in,
                                                 f16* __restrict__ out, int n) {
    int i = (blockIdx.x * 256 + threadIdx.x) * 4;
    if (i + 3 < n) {
        float4 v = *(const float4*)(in + i);
        f16x4 o = {(f16)v.x, (f16)v.y, (f16)v.z, (f16)v.w};
        *(f16x4*)(out + i) = o;
    }
}

// ---------------- transpose + cast all four 1024x1024 weights in one launch ----------------
__global__ __launch_bounds__(256) void k_transpose_w4(const float* __restrict__ Wq,
                                                      const float* __restrict__ Wk,
                                                      const float* __restrict__ Wv,
                                                      const float* __restrict__ Wr,
                                                      f16* __restrict__ Wqkvt,
                                                      f16* __restrict__ Wrt) {
    __shared__ float tile[32][33];
    int z = blockIdx.z;
    const float* W = (z == 0) ? Wq : (z == 1) ? Wk : (z == 2) ? Wv : Wr;
    f16* Wt = (z == 3) ? Wrt : Wqkvt + z * 1048576;
    int c0 = blockIdx.x * 32, r0 = blockIdx.y * 32;
    int tx = threadIdx.x, ty = threadIdx.y;  // 32 x 8
#pragma unroll
    for (int j = 0; j < 32; j += 8)
        tile[ty + j][tx] = W[(r0 + ty + j) * 1024 + c0 + tx];
    __syncthreads();
#pragma unroll
    for (int j = 0; j < 32; j += 8)
        Wt[(c0 + ty + j) * 1024 + r0 + tx] = (f16)tile[tx][ty + j];
}

// ---------------- transpose V slice of QKV into Vt[bh][d][s] ----------------
__global__ __launch_bounds__(256) void k_transpose_v(const f16* __restrict__ QKV,
                                                     f16* __restrict__ Vt) {
    __shared__ f16 tile[32][33];
    int s0 = blockIdx.x * 32;
    int d0 = blockIdx.y * 32;
    int bh = blockIdx.z;
    int b = bh >> 4, h = bh & 15;
    int tx = threadIdx.x, ty = threadIdx.y;  // 32 x 8
#pragma unroll
    for (int j = 0; j < 32; j += 8)
        tile[ty + j][tx] = QKV[(b * 2048 + s0 + ty + j) * 3072 + 2048 + h * 64 + d0 + tx];
    __syncthreads();
#pragma unroll
    for (int j = 0; j < 32; j += 8)
        Vt[(bh * 64 + d0 + ty + j) * 2048 + s0 + tx] = tile[tx][ty + j];
}

// ---------------- GEMM: C[M][N] = A[M][K] * Bt[N][K]^T, 32x32x16 MFMA ----------------
template <bool OUT_F16>
__global__ __launch_bounds__(256, 4) void k_gemm_bt(const f16* __restrict__ A,
                                                    const f16* __restrict__ Bt,
                                                    void* __restrict__ Cv,
                                                    int M, int N, int K) {
    __shared__ f16 As[128][32];
    __shared__ f16 Bs[128][32];
    int t = threadIdx.x;
    int lane = t & 63, w = t >> 6;
    int wm = (w >> 1) * 64, wn = (w & 1) * 64;
    int m0 = blockIdx.y * 128, n0 = blockIdx.x * 128;
    int ln = lane & 31, kh = lane >> 5;
    int sw = (ln >> 1) & 3;

    int lin0 = w * 128 + lane, lin1 = lin0 + 64;
    int r0 = lin0 >> 2, c0 = (lin0 & 3) ^ ((r0 >> 1) & 3);
    int r1 = lin1 >> 2, c1 = (lin1 & 3) ^ ((r1 >> 1) & 3);
    const f16* gA0 = A + (size_t)(m0 + r0) * K + c0 * 8;
    const f16* gA1 = A + (size_t)(m0 + r1) * K + c1 * 8;
    const f16* gB0 = Bt + (size_t)(n0 + r0) * K + c0 * 8;
    const f16* gB1 = Bt + (size_t)(n0 + r1) * K + c1 * 8;
    f16* lA0 = &As[0][0] + w * 1024;
    f16* lB0 = &Bs[0][0] + w * 1024;

    f32x16 acc[2][2] = {};

    for (int k0 = 0; k0 < K; k0 += 32) {
        __syncthreads();
        async16(lA0, gA0 + k0);
        async16(lA0 + 512, gA1 + k0);
        async16(lB0, gB0 + k0);
        async16(lB0 + 512, gB1 + k0);
        __syncthreads();
#pragma unroll
        for (int kd = 0; kd < 2; kd++) {
            int c = kd * 2 + kh;
            f16x8 af[2], bf[2];
#pragma unroll
            for (int mt = 0; mt < 2; mt++)
                af[mt] = *(const f16x8*)&As[wm + mt * 32 + ln][(c ^ sw) * 8];
#pragma unroll
            for (int nt = 0; nt < 2; nt++)
                bf[nt] = *(const f16x8*)&Bs[wn + nt * 32 + ln][(c ^ sw) * 8];
#pragma unroll
            for (int mt = 0; mt < 2; mt++)
#pragma unroll
                for (int nt = 0; nt < 2; nt++)
                    acc[mt][nt] = MFMA32(af[mt], bf[nt], acc[mt][nt]);
        }
    }

#pragma unroll
    for (int mt = 0; mt < 2; mt++)
#pragma unroll
        for (int nt = 0; nt < 2; nt++)
#pragma unroll
            for (int r = 0; r < 16; r++) {
                int row = m0 + wm + mt * 32 + (r & 3) + 8 * (r >> 2) + 4 * kh;
                int col = n0 + wn + nt * 32 + ln;
                float v = acc[mt][nt][r];
                if (OUT_F16)
                    ((f16*)Cv)[(size_t)row * N + col] = (f16)v;
                else
                    ((float*)Cv)[(size_t)row * N + col] = v;
            }
}

// ---------------- flash attention v8: barrier-free, LDS-free, 1 wave / workgroup -----
// Each 64-thread block = ONE wave owning 32 q rows. No __syncthreads, no LDS: MFMA
// fragments load straight from global (L2-hot; a 16B/lane fragment gather touches the
// same 16x64B cache lines as a coalesced dwordx4). Split-K + fp32 atomic epilogue
// (proven r7). blockIdx.y packs (khalf, p, wq): phases qt = 15-p then p, each wave
// processes its k-half; per-wave tile counts vary freely (no lockstep).
__global__ __launch_bounds__(64) void k_attn(const f16* __restrict__ QKV,
                                             const f16* __restrict__ Vt,
                                             float* __restrict__ Oacc,
                                             float* __restrict__ Lacc) {
    int bh = blockIdx.x;
    int y = blockIdx.y;        // 0..63
    int khalf = y >> 5;        // 0..1
    int p = (y >> 2) & 7;      // 0..7  (heavy qt=15-p dispatch first)
    int wq = y & 3;            // which 32-row slice of the 128-row q-tile
    int b = bh >> 4, h = bh & 15;
    int lane = threadIdx.x;
    int ln = lane & 15, g = lane >> 4, g8 = g * 8, rg = g * 4;

    const f16* Kbase = QKV + (size_t)b * 2048 * 3072 + 1024 + h * 64;
    const f16* Vbase = Vt + (size_t)bh * 64 * 2048;

    const float C_SCL = 0.18033688f;  // 0.125 * log2(e)
    const float C_MSK = -72.134752f;  // -50 * log2(e)

    // lane-constant element offsets (kd*32 / mt*16 folded into the 13-bit imm offset)
    int vko[4], vvo[4];
#pragma unroll
    for (int mt = 0; mt < 4; mt++) vko[mt] = (mt * 16 + ln) * 3072 + g8;
#pragma unroll
    for (int dt = 0; dt < 4; dt++) vvo[dt] = (dt * 16 + ln) * 2048 + rg;

    for (int phase = 0; phase < 2; phase++) {
        int qt = phase ? p : (15 - p);
        int q0 = qt * 128;
        int qw = q0 + wq * 32;           // this wave's 32 q rows
        int cnt = qt + 1;                // tiles per k-half for this q-tile
        int s = khalf * cnt;
        int jhi = 2 * qt + (wq >> 1);    // last k-tile this wave actually needs
        int cntw = jhi - s + 1;
        cntw = cntw < 0 ? 0 : (cntw > cnt ? cnt : cntw);

        // Q fragments (B-operand of S^T = K.Q^T)
        f16x8 bq[2][2];
#pragma unroll
        for (int nt = 0; nt < 2; nt++)
#pragma unroll
            for (int kd = 0; kd < 2; kd++)
                bq[nt][kd] = *(const f16x8*)(QKV +
                    (size_t)(b * 2048 + qw + nt * 16 + ln) * 3072 + h * 64 + kd * 32 + g8);

        f32x4 oacc[2][4] = {};  // [nt: q16][dt: d16]
        float lsum[2] = {0.f, 0.f};

        for (int j = 0; j < cntw; j++) {
            int k0 = (s + j) * 64;
            const f16* Kp = Kbase + (size_t)k0 * 3072;
            const f16* Vp = Vbase + k0;

            // issue all 24 fragment loads up front; S-MFMA only waits on the 8 ak
            // (vmcnt>0), so the 16 bv stay in flight behind S + exp.
            f16x8 ak[2][4];
#pragma unroll
            for (int mt = 0; mt < 4; mt++)
#pragma unroll
                for (int kd = 0; kd < 2; kd++)
                    ak[kd][mt] = *(const f16x8*)(Kp + vko[mt] + kd * 32);
            f16x4 bv[4][4];
#pragma unroll
            for (int mt = 0; mt < 4; mt++)
#pragma unroll
                for (int dt = 0; dt < 4; dt++)
                    bv[mt][dt] = *(const f16x4*)(Vp + vvo[dt] + mt * 16);

            // S^T tile: D[m=k 64][n=q 32]
            f32x4 sacc[4][2] = {};
#pragma unroll
            for (int kd = 0; kd < 2; kd++)
#pragma unroll
                for (int mt = 0; mt < 4; mt++)
#pragma unroll
                    for (int nt = 0; nt < 2; nt++)
                        sacc[mt][nt] = MFMA16(ak[kd][mt], bq[nt][kd], sacc[mt][nt]);

            // fixed-max softmax numerator -> P in registers; PV per mt
            bool needs_mask = (k0 + 63 > qw);
#pragma unroll
            for (int mt = 0; mt < 4; mt++) {
                f16x4 pk[2];
#pragma unroll
                for (int nt = 0; nt < 2; nt++) {
                    int q = qw + nt * 16 + ln;
#pragma unroll
                    for (int r = 0; r < 4; r++) {
                        float e;
                        if (needs_mask) {
                            int kk = k0 + mt * 16 + rg + r;
                            e = __builtin_amdgcn_exp2f(
                                fmaf(sacc[mt][nt][r], C_SCL, (kk > q) ? C_MSK : 0.f));
                        } else {
                            e = __builtin_amdgcn_exp2f(sacc[mt][nt][r] * C_SCL);
                        }
                        lsum[nt] += e;
                        pk[nt][r] = (f16)e;
                    }
                }
#pragma unroll
                for (int nt = 0; nt < 2; nt++)
#pragma unroll
                    for (int dt = 0; dt < 4; dt++)
                        oacc[nt][dt] = MFMA16K16(pk[nt], bv[mt][dt], oacc[nt][dt]);
            }
        }

        // row sums: reduce per-lane partials across the 4 k-register groups (g)
#pragma unroll
        for (int nt = 0; nt < 2; nt++) {
            float rs = lsum[nt];
            rs += __shfl_xor(rs, 16, 64);
            rs += __shfl_xor(rs, 32, 64);
            lsum[nt] = rs;
        }

        // fp32 atomic accumulate of unnormalized partials
#pragma unroll
        for (int nt = 0; nt < 2; nt++)
#pragma unroll
            for (int r = 0; r < 4; r++) {
                int q = qw + nt * 16 + rg + r;
                size_t row = (size_t)(b * 2048 + q);
#pragma unroll
                for (int dt = 0; dt < 4; dt++)
                    atomicAdd(&Oacc[row * 1024 + h * 64 + dt * 16 + ln],
                              oacc[nt][dt][r]);
            }
        if (g == 0) {
#pragma unroll
            for (int nt = 0; nt < 2; nt++)
                atomicAdd(&Lacc[(size_t)bh * 2048 + qw + nt * 16 + ln], lsum[nt]);
        }
    }
}

// ---------------- normalize partials -> f16 O ----------------
__global__ __launch_bounds__(256) void k_finalize(const float* __restrict__ Oacc,
                                                  const float* __restrict__ Lacc,
                                                  f16* __restrict__ Ob) {
    int i = (blockIdx.x * 256 + threadIdx.x) * 4;  // over 8192*1024 f32
    int row = i >> 10, col = i & 1023;             // row = b*2048 + q
    int b = row >> 11, q = row & 2047, h = col >> 6;
    float inv = __builtin_amdgcn_rcpf(Lacc[(size_t)(b * 16 + h) * 2048 + q]);
    float4 v = *(const float4*)(Oacc + i);
    f16x4 o = {(f16)(v.x * inv), (f16)(v.y * inv), (f16)(v.z * inv), (f16)(v.w * inv)};
    *(f16x4*)(Ob + i) = o;
}

// ---------------- host launch ----------------
extern "C" void kernel_launch(void* const* d_in, const int* in_sizes, int n_in,
                              void* d_out, int out_size, void* d_ws, size_t ws_size,
                              hipStream_t stream) {
    const float* x = (const float*)d_in[0];
    const float* Wq = (const float*)d_in[1];
    const float* Wk = (const float*)d_in[2];
    const float* Wv = (const float*)d_in[3];
    const float* Wr = (const float*)d_in[4];
    float* out = (float*)d_out;

    f16* ws = (f16*)d_ws;
    f16* xb    = ws;                    // 8192*1024
    f16* Wqkvt = xb + 8388608;          // 3072*1024
    f16* Wrt   = Wqkvt + 3145728;       // 1024*1024
    f16* QKVb  = Wrt + 1048576;         // 8192*3072
    f16* Vtb   = QKVb + 25165824;       // 64bh * 64d * 2048s
    f16* Obuf  = Vtb + 8388608;         // 8192*1024
    float* Lacc = (float*)(Obuf + 8388608);  // 64bh * 2048q fp32 (0.5 MB)
    float* Oacc = out;  // reuse d_out (8192x1024 f32) as attention partial-sum scratch

    k_convert<<<8192, 256, 0, stream>>>(x, xb, 8388608);
    dim3 tb(32, 8);
    k_transpose_w4<<<dim3(32, 32, 4), tb, 0, stream>>>(Wq, Wk, Wv, Wr, Wqkvt, Wrt);
    k_gemm_bt<true><<<dim3(24, 64), 256, 0, stream>>>(xb, Wqkvt, QKVb, 8192, 3072, 1024);
    k_transpose_v<<<dim3(64, 2, 64), tb, 0, stream>>>(QKVb, Vtb);
    hipMemsetAsync(Oacc, 0, (size_t)8388608 * 4, stream);
    hipMemsetAsync(Lacc, 0, (size_t)131072 * 4, stream);
    k_attn<<<dim3(64, 64), 64, 0, stream>>>(QKVb, Vtb, Oacc, Lacc);
    k_finalize<<<8192, 256, 0, stream>>>(Oacc, Lacc, Obuf);
    k_gemm_bt<false><<<dim3(8, 64), 256, 0, stream>>>(Obuf, Wrt, out, 8192, 1024, 1024);
}